// Round 1
// baseline (5027.452 us; speedup 1.0000x reference)
//
#include <hip/hip_runtime.h>
#include <hip/hip_bf16.h>

#define S_ 2048
#define E_ 1024
#define B_ 2
#define H_ 16
#define BT 128   // output tile edge
#define BKE 64   // contraction step (elements)

typedef __bf16 bfvec8 __attribute__((ext_vector_type(8)));
typedef float  f32x4  __attribute__((ext_vector_type(4)));

__device__ inline f32x4 mfma16(bfvec8 a, bfvec8 b, f32x4 c){
  return __builtin_amdgcn_mfma_f32_16x16x32_bf16(a, b, c, 0, 0, 0);
}

__device__ inline unsigned short f2b(float f){
  __hip_bfloat16 h = __float2bfloat16(f);
  union { __hip_bfloat16 h; unsigned short u; } cv;
  cv.h = h; return cv.u;
}

// ---- staging: load f32 q/k tile, apply per-head diag scale + rope, write bf16 to swizzled LDS
// LDS tile: BT rows x BKE cols bf16, row pitch 128B, swizzle byte ^= (row&7)<<4
__device__ inline void stage_rope(char* ldsT, const float* __restrict__ src,
                                  const float* __restrict__ Wrow,
                                  const float2* __restrict__ cs,
                                  int row0, int e0, int t){
  const int row  = t >> 1;
  const int colb = (t & 1) * 32;
  const int s    = row0 + row;
  const float*  sp = src  + (size_t)s * E_ + e0 + colb;
  const float*  wp = Wrow + e0 + colb;
  const float2* cp = cs   + (size_t)s * (E_/2) + ((e0 + colb) >> 1);
  #pragma unroll
  for (int c = 0; c < 4; ++c) {
    float4 xa = *(const float4*)(sp + c*8);
    float4 xb = *(const float4*)(sp + c*8 + 4);
    float4 wa = *(const float4*)(wp + c*8);
    float4 wb = *(const float4*)(wp + c*8 + 4);
    float2 f0 = cp[c*4+0], f1 = cp[c*4+1], f2 = cp[c*4+2], f3 = cp[c*4+3];
    union { bfvec8 bv; uint4 u4; } pk;
    float t0, t1;
    t0 = wa.x*xa.x; t1 = wa.y*xa.y;
    pk.bv[0] = (__bf16)(f0.x*t0 - f0.y*t1);
    pk.bv[1] = (__bf16)(f0.x*t1 + f0.y*t0);
    t0 = wa.z*xa.z; t1 = wa.w*xa.w;
    pk.bv[2] = (__bf16)(f1.x*t0 - f1.y*t1);
    pk.bv[3] = (__bf16)(f1.x*t1 + f1.y*t0);
    t0 = wb.x*xb.x; t1 = wb.y*xb.y;
    pk.bv[4] = (__bf16)(f2.x*t0 - f2.y*t1);
    pk.bv[5] = (__bf16)(f2.x*t1 + f2.y*t0);
    t0 = wb.z*xb.z; t1 = wb.w*xb.w;
    pk.bv[6] = (__bf16)(f3.x*t0 - f3.y*t1);
    pk.bv[7] = (__bf16)(f3.x*t1 + f3.y*t0);
    const int byte = (row*128 + (colb + c*8)*2) ^ ((row & 7) << 4);
    *(uint4*)(ldsT + byte) = pk.u4;
  }
}

// plain bf16 tile copy (K5): src row-major pitch elements -> swizzled LDS
__device__ inline void stage_copy(char* ldsT, const unsigned short* __restrict__ src,
                                  size_t pitch, int row0, int col0, int t){
  const int row = t >> 1, colb = (t & 1) * 32;
  const unsigned short* sp = src + (size_t)(row0 + row) * pitch + col0 + colb;
  #pragma unroll
  for (int c = 0; c < 4; ++c){
    uint4 val = *(const uint4*)(sp + c*8);
    const int byte = (row*128 + (colb + c*8)*2) ^ ((row & 7) << 4);
    *(uint4*)(ldsT + byte) = val;
  }
}

__device__ inline bfvec8 read_frag(const char* ldsT, int row, int kh2, int lane){
  const int byte = (row*128 + kh2*64 + ((lane >> 4) << 4)) ^ ((row & 7) << 4);
  return *(const bfvec8*)(ldsT + byte);
}

// ---- K1: rope tables cs[s][j] = (cos, sin), ang = s * 10000^(-2j/E)
__global__ void k1_tab(float2* __restrict__ cs){
  const int idx = blockIdx.x * 256 + threadIdx.x;   // S_*512 total
  const int s = idx >> 9, j = idx & 511;
  const float ex  = -(float)(2*j) * (13.287712379549449f / 1024.0f); // log2(10000)/E * (-2j)
  const float inv = exp2f(ex);
  const float ang = (float)s * inv;
  float sn, c;
  sincosf(ang, &sn, &c);
  cs[idx] = make_float2(c, sn);
}

// ---- K2: vt[b][e][s] = bf16(v[b][s][e])
__global__ void k2_tr(const float* __restrict__ v, unsigned short* __restrict__ vt){
  __shared__ float tile[64][65];
  const int b = blockIdx.z, s0 = blockIdx.x*64, e0 = blockIdx.y*64;
  const int tx = threadIdx.x, ty = threadIdx.y;
  const float* vb = v + ((size_t)b*S_ + s0)*E_ + e0;
  #pragma unroll
  for (int i=0;i<4;i++){
    const int r = ty + i*16;
    float4 x = *(const float4*)(vb + (size_t)r*E_ + tx*4);
    tile[r][tx*4+0]=x.x; tile[r][tx*4+1]=x.y; tile[r][tx*4+2]=x.z; tile[r][tx*4+3]=x.w;
  }
  __syncthreads();
  unsigned short* vtb = vt + ((size_t)b*E_ + e0)*S_ + s0;
  #pragma unroll
  for (int i=0;i<4;i++){
    const int er = ty + i*16;
    ushort4 o;
    o.x = f2b(tile[tx*4+0][er]);
    o.y = f2b(tile[tx*4+1][er]);
    o.z = f2b(tile[tx*4+2][er]);
    o.w = f2b(tile[tx*4+3][er]);
    *(ushort4*)(vtb + (size_t)er*S_ + tx*4) = o;
  }
}

// ---- K3: linv[b][h][q] = 1 / sum_{k<=q} exp(s_h[q,k])
// swapped mfma(K,Q): tile rows = k, cols = q
__global__ __launch_bounds__(256) void k3_linv(const float* __restrict__ q, const float* __restrict__ kk_,
                                               const float* __restrict__ W, const float2* __restrict__ cs,
                                               float* __restrict__ linv){
  const int qb = blockIdx.x, h = blockIdx.y, b = blockIdx.z;
  const int t = threadIdx.x, lane = t & 63, wid = t >> 6;
  const int wr = wid >> 1, wc = wid & 1;
  __shared__ __align__(16) char ldsK[BT*BKE*2];
  __shared__ __align__(16) char ldsQ[BT*BKE*2];
  __shared__ float lsh[BT];
  const float* qsrc = q   + (size_t)b*S_*E_;
  const float* ksrc = kk_ + (size_t)b*S_*E_;
  const float* Wrow = W + h*E_;
  const int q0 = qb*BT;
  const f32x4 z4 = {0.f,0.f,0.f,0.f};
  float lpart[4] = {0.f,0.f,0.f,0.f};
  for (int kt = 0; kt <= qb; ++kt){
    const int k0 = kt*BT;
    f32x4 acc[4][4];
    #pragma unroll
    for (int m=0;m<4;m++)
      #pragma unroll
      for (int n=0;n<4;n++) acc[m][n] = z4;
    for (int et = 0; et < E_/BKE; ++et){
      __syncthreads();
      stage_rope(ldsK, ksrc, Wrow, cs, k0, et*BKE, t);
      stage_rope(ldsQ, qsrc, Wrow, cs, q0, et*BKE, t);
      __syncthreads();
      #pragma unroll
      for (int kh2=0; kh2<2; ++kh2){
        bfvec8 af[4], bfv[4];
        #pragma unroll
        for (int m=0;m<4;m++) af[m]  = read_frag(ldsK, wr*64 + m*16 + (lane&15), kh2, lane);
        #pragma unroll
        for (int n=0;n<4;n++) bfv[n] = read_frag(ldsQ, wc*64 + n*16 + (lane&15), kh2, lane);
        #pragma unroll
        for (int m=0;m<4;m++)
          #pragma unroll
          for (int n=0;n<4;n++)
            acc[m][n] = mfma16(af[m], bfv[n], acc[m][n]);
      }
    }
    const bool partial = (kt == qb);
    #pragma unroll
    for (int n=0;n<4;n++){
      const int qg = q0 + wc*64 + n*16 + (lane&15);
      float ssum = 0.f;
      #pragma unroll
      for (int m=0;m<4;m++){
        const int kgb = k0 + wr*64 + m*16 + ((lane>>4)<<2);
        #pragma unroll
        for (int r=0;r<4;r++){
          const float e = __expf(acc[m][n][r]);
          if (!partial || (kgb + r) <= qg) ssum += e;
        }
      }
      lpart[n] += ssum;
    }
  }
  if (t < BT) lsh[t] = 0.f;
  __syncthreads();
  #pragma unroll
  for (int n=0;n<4;n++)
    atomicAdd(&lsh[wc*64 + n*16 + (lane&15)], lpart[n]);
  __syncthreads();
  if (t < BT)
    linv[((size_t)b*H_ + h)*S_ + q0 + t] = 1.0f / lsh[t];
}

// ---- K4: At[b][k][q] = sum_h lr_h * exp(s_h[q,k]) * linv_h[q]  (k<q strict; else 0), bf16
__global__ __launch_bounds__(256) void k4_A(const float* __restrict__ q, const float* __restrict__ kk_,
                                            const float* __restrict__ W, const float2* __restrict__ cs,
                                            const float* __restrict__ linv, const float* __restrict__ lr,
                                            unsigned short* __restrict__ At){
  const int qb = blockIdx.x, kb = blockIdx.y, b = blockIdx.z;
  const int t = threadIdx.x;
  unsigned short* Atb = At + (size_t)b*S_*S_;
  const int q0 = qb*BT, k0 = kb*BT;
  if (qb < kb){   // entire tile is q <= k: zeros
    const int row = t >> 1, colb = (t & 1)*64;
    uint4 z = make_uint4(0u,0u,0u,0u);
    unsigned short* p = Atb + (size_t)(k0 + row)*S_ + q0 + colb;
    #pragma unroll
    for (int c=0;c<8;c++) *(uint4*)(p + c*8) = z;
    return;
  }
  const int lane = t & 63, wid = t >> 6, wr = wid >> 1, wc = wid & 1;
  __shared__ __align__(16) char ldsK[BT*BKE*2];
  __shared__ __align__(16) char ldsQ[BT*BKE*2];
  __shared__ float lsh[BT];
  const float* qsrc = q   + (size_t)b*S_*E_;
  const float* ksrc = kk_ + (size_t)b*S_*E_;
  const bool diag = (qb == kb);
  const f32x4 z4 = {0.f,0.f,0.f,0.f};
  f32x4 Aacc[4][4];
  #pragma unroll
  for (int m=0;m<4;m++)
    #pragma unroll
    for (int n=0;n<4;n++) Aacc[m][n] = z4;

  for (int h = 0; h < H_; ++h){
    __syncthreads();
    if (t < BT) lsh[t] = linv[((size_t)b*H_ + h)*S_ + q0 + t];
    const float* Wrow = W + h*E_;
    const float lrh = lr[h];
    f32x4 acc[4][4];
    #pragma unroll
    for (int m=0;m<4;m++)
      #pragma unroll
      for (int n=0;n<4;n++) acc[m][n] = z4;
    for (int et = 0; et < E_/BKE; ++et){
      __syncthreads();
      stage_rope(ldsK, ksrc, Wrow, cs, k0, et*BKE, t);
      stage_rope(ldsQ, qsrc, Wrow, cs, q0, et*BKE, t);
      __syncthreads();
      #pragma unroll
      for (int kh2=0; kh2<2; ++kh2){
        bfvec8 af[4], bfv[4];
        #pragma unroll
        for (int m=0;m<4;m++) af[m]  = read_frag(ldsK, wr*64 + m*16 + (lane&15), kh2, lane);
        #pragma unroll
        for (int n=0;n<4;n++) bfv[n] = read_frag(ldsQ, wc*64 + n*16 + (lane&15), kh2, lane);
        #pragma unroll
        for (int m=0;m<4;m++)
          #pragma unroll
          for (int n=0;n<4;n++)
            acc[m][n] = mfma16(af[m], bfv[n], acc[m][n]);
      }
    }
    #pragma unroll
    for (int n=0;n<4;n++){
      const int ql = wc*64 + n*16 + (lane&15);
      const float wgt = lrh * lsh[ql];
      const int qg = q0 + ql;
      #pragma unroll
      for (int m=0;m<4;m++){
        const int kgb = k0 + wr*64 + m*16 + ((lane>>4)<<2);
        #pragma unroll
        for (int r=0;r<4;r++){
          const float p = __expf(acc[m][n][r]) * wgt;
          if (!diag || (kgb + r) < qg) Aacc[m][n][r] += p;
        }
      }
    }
  }
  #pragma unroll
  for (int m=0;m<4;m++){
    #pragma unroll
    for (int r=0;r<4;r++){
      const int kl = wr*64 + m*16 + ((lane>>4)<<2) + r;
      unsigned short* p = Atb + (size_t)(k0 + kl)*S_ + q0;
      #pragma unroll
      for (int n=0;n<4;n++){
        const int ql = wc*64 + n*16 + (lane&15);
        p[ql] = f2b(Aacc[m][n][r]);
      }
    }
  }
}

// ---- K5: out[b][k][d] = (1/(k+1)) * sum_q At[b][k][q] * v[b][q][d]
__global__ __launch_bounds__(256) void k5_out(const unsigned short* __restrict__ At,
                                              const unsigned short* __restrict__ vt,
                                              float* __restrict__ out){
  const int db = blockIdx.x, kb = blockIdx.y, b = blockIdx.z;
  const int t = threadIdx.x, lane = t & 63, wid = t >> 6, wr = wid >> 1, wc = wid & 1;
  __shared__ __align__(16) char ldsA[BT*BKE*2];
  __shared__ __align__(16) char ldsV[BT*BKE*2];
  const unsigned short* Atb = At + (size_t)b*S_*S_;
  const unsigned short* vtb = vt + (size_t)b*E_*S_;
  const int k0 = kb*BT, d0 = db*BT;
  const f32x4 z4 = {0.f,0.f,0.f,0.f};
  f32x4 acc[4][4];
  #pragma unroll
  for (int m=0;m<4;m++)
    #pragma unroll
    for (int n=0;n<4;n++) acc[m][n] = z4;
  for (int qt = kb*2; qt < S_/BKE; ++qt){   // only q-chunks with q > k contribute
    const int qq0 = qt*BKE;
    __syncthreads();
    stage_copy(ldsA, Atb, S_, k0, qq0, t);
    stage_copy(ldsV, vtb, S_, d0, qq0, t);
    __syncthreads();
    #pragma unroll
    for (int kh2=0; kh2<2; ++kh2){
      bfvec8 af[4], bfv[4];
      #pragma unroll
      for (int m=0;m<4;m++) af[m]  = read_frag(ldsA, wr*64 + m*16 + (lane&15), kh2, lane);
      #pragma unroll
      for (int n=0;n<4;n++) bfv[n] = read_frag(ldsV, wc*64 + n*16 + (lane&15), kh2, lane);
      #pragma unroll
      for (int m=0;m<4;m++)
        #pragma unroll
        for (int n=0;n<4;n++)
          acc[m][n] = mfma16(af[m], bfv[n], acc[m][n]);
    }
  }
  #pragma unroll
  for (int m=0;m<4;m++){
    #pragma unroll
    for (int r=0;r<4;r++){
      const int kg = k0 + wr*64 + m*16 + ((lane>>4)<<2) + r;
      const float ns = 1.0f / (float)(kg + 1);
      float* p = out + ((size_t)b*S_ + kg)*E_ + d0;
      #pragma unroll
      for (int n=0;n<4;n++){
        const int dl = wc*64 + n*16 + (lane&15);
        p[dl] = acc[m][n][r] * ns;
      }
    }
  }
}

extern "C" void kernel_launch(void* const* d_in, const int* in_sizes, int n_in,
                              void* d_out, int out_size, void* d_ws, size_t ws_size,
                              hipStream_t stream){
  const float* q  = (const float*)d_in[0];
  const float* k  = (const float*)d_in[1];
  const float* v  = (const float*)d_in[2];
  const float* W  = (const float*)d_in[3];
  const float* lr = (const float*)d_in[4];
  float* out = (float*)d_out;

  char* ws = (char*)d_ws;
  float2* cs = (float2*)ws;
  size_t off = (size_t)S_ * (E_/2) * sizeof(float2);           // 8 MB
  float* linv = (float*)(ws + off);  off += (size_t)B_*H_*S_*sizeof(float);   // 256 KB
  unsigned short* At = (unsigned short*)(ws + off); off += (size_t)B_*S_*S_*2; // 16.8 MB
  unsigned short* vt = (unsigned short*)(ws + off); off += (size_t)B_*E_*S_*2; // 8.4 MB
  (void)ws_size; (void)in_sizes; (void)n_in; (void)out_size;

  k1_tab<<<dim3((S_*512)/256), dim3(256), 0, stream>>>(cs);
  k2_tr <<<dim3(S_/64, E_/64, B_), dim3(16,16), 0, stream>>>(v, vt);
  k3_linv<<<dim3(S_/BT, H_, B_), dim3(256), 0, stream>>>(q, k, W, cs, linv);
  k4_A  <<<dim3(S_/BT, S_/BT, B_), dim3(256), 0, stream>>>(q, k, W, cs, linv, lr, At);
  k5_out<<<dim3(E_/BT, S_/BT, B_), dim3(256), 0, stream>>>(At, vt, out);
}

// Round 3
// 914.814 us; speedup vs baseline: 5.4956x; 5.4956x over previous
//
#include <hip/hip_runtime.h>
#include <hip/hip_bf16.h>

#define S_ 2048
#define E_ 1024
#define B_ 2
#define H_ 16
#define G_ 4      // heads per group
#define BT 128
#define BKE 64

typedef __bf16 bfvec8 __attribute__((ext_vector_type(8)));
typedef float  f32x4  __attribute__((ext_vector_type(4)));

__device__ inline f32x4 mfma16(bfvec8 a, bfvec8 b, f32x4 c){
  return __builtin_amdgcn_mfma_f32_16x16x32_bf16(a, b, c, 0, 0, 0);
}

__device__ inline void tri_decode(int idx, int& qb, int& kt){
  int q = (int)((sqrtf(8.0f*(float)idx + 1.0f) - 1.0f) * 0.5f);
  while ((q+1)*(q+2)/2 <= idx) ++q;
  while (q*(q+1)/2 > idx) --q;
  qb = q; kt = idx - q*(q+1)/2;
}

// ---- LDS staging helpers: tile row pitch 128B, swizzle byte ^= (row&7)<<4 ----
__device__ inline void stage128(char* lds, const unsigned short* __restrict__ src, int pitch, int t){
  const int row = t >> 1, cb = (t & 1) * 32;
  const unsigned short* sp = src + (size_t)row*pitch + cb;
  #pragma unroll
  for (int c = 0; c < 4; ++c){
    uint4 v = *(const uint4*)(sp + c*8);
    const int byte = (row*128 + (cb + c*8)*2) ^ ((row & 7) << 4);
    *(uint4*)(lds + byte) = v;
  }
}

__device__ inline void stage64(char* lds, const unsigned short* __restrict__ src, int pitch, int t){
  const int row = t >> 2, cb = (t & 3) * 16;
  const unsigned short* sp = src + (size_t)row*pitch + cb;
  #pragma unroll
  for (int c = 0; c < 2; ++c){
    uint4 v = *(const uint4*)(sp + c*8);
    const int byte = (row*128 + (cb + c*8)*2) ^ ((row & 7) << 4);
    *(uint4*)(lds + byte) = v;
  }
}

__device__ inline void stagecvt128(char* lds, const float* __restrict__ src, int pitch, int t){
  const int row = t >> 1, cb = (t & 1) * 32;
  const float* sp = src + (size_t)row*pitch + cb;
  #pragma unroll
  for (int c = 0; c < 4; ++c){
    float4 a = *(const float4*)(sp + c*8);
    float4 b = *(const float4*)(sp + c*8 + 4);
    union { bfvec8 v; uint4 u; } pk;
    pk.v[0]=(__bf16)a.x; pk.v[1]=(__bf16)a.y; pk.v[2]=(__bf16)a.z; pk.v[3]=(__bf16)a.w;
    pk.v[4]=(__bf16)b.x; pk.v[5]=(__bf16)b.y; pk.v[6]=(__bf16)b.z; pk.v[7]=(__bf16)b.w;
    const int byte = (row*128 + (cb + c*8)*2) ^ ((row & 7) << 4);
    *(uint4*)(lds + byte) = pk.u;
  }
}

__device__ inline bfvec8 read_frag(const char* lds, int row, int kh2, int lane){
  const int byte = (row*128 + kh2*64 + ((lane >> 4) << 4)) ^ ((row & 7) << 4);
  return *(const bfvec8*)(lds + byte);
}

// ---- zero l + At_f32 ----
__global__ void kz(float4* __restrict__ p, int n4){
  const float4 z = make_float4(0.f,0.f,0.f,0.f);
  for (int i = blockIdx.x*256 + threadIdx.x; i < n4; i += gridDim.x*256) p[i] = z;
}

// ---- k0: q̂,k̂ bf16 for heads g*G_..g*G_+G_-1 ----
__global__ __launch_bounds__(256) void k0_prep(const float* __restrict__ q, const float* __restrict__ k,
                                               const float* __restrict__ W,
                                               unsigned short* __restrict__ qh, unsigned short* __restrict__ kh,
                                               int g){
  const int tid = blockIdx.x*256 + threadIdx.x;   // [0, S*E/8)
  const int e0 = (tid & 127) * 8;
  const int s  = tid >> 7;
  const int hp = blockIdx.y, b = blockIdx.z;
  const int h  = g*G_ + hp;
  const float* qp = q + ((size_t)b*S_ + s)*E_ + e0;
  const float* kp = k + ((size_t)b*S_ + s)*E_ + e0;
  const float* wp = W + (size_t)h*E_ + e0;
  float xq[8], xk[8], xw[8];
  *(float4*)&xq[0] = *(const float4*)qp;  *(float4*)&xq[4] = *(const float4*)(qp+4);
  *(float4*)&xk[0] = *(const float4*)kp;  *(float4*)&xk[4] = *(const float4*)(kp+4);
  *(float4*)&xw[0] = *(const float4*)wp;  *(float4*)&xw[4] = *(const float4*)(wp+4);
  union { bfvec8 v; uint4 u; } oq, ok;
  const float base = -13.287712379549449f / 1024.0f;   // -log2(10000)*2/E
  #pragma unroll
  for (int p = 0; p < 4; ++p){
    const int j = (e0 >> 1) + p;
    const float inv = exp2f((float)(2*j) * base);
    float sn, cn;
    sincosf((float)s * inv, &sn, &cn);
    float t0 = xw[2*p]*xq[2*p], t1 = xw[2*p+1]*xq[2*p+1];
    oq.v[2*p]   = (__bf16)(t0*cn - t1*sn);
    oq.v[2*p+1] = (__bf16)(t1*cn + t0*sn);
    t0 = xw[2*p]*xk[2*p]; t1 = xw[2*p+1]*xk[2*p+1];
    ok.v[2*p]   = (__bf16)(t0*cn - t1*sn);
    ok.v[2*p+1] = (__bf16)(t1*cn + t0*sn);
  }
  const size_t o = (((size_t)b*G_ + hp)*S_ + s)*E_ + e0;
  *(uint4*)(qh + o) = oq.u;
  *(uint4*)(kh + o) = ok.u;
}

// ---- k2: vt[b][e][s] = bf16(v[b][s][e]) ----
__global__ void k2_tr(const float* __restrict__ v, unsigned short* __restrict__ vt){
  __shared__ float tile[64][65];
  const int b = blockIdx.z, s0 = blockIdx.x*64, e0 = blockIdx.y*64;
  const int tx = threadIdx.x, ty = threadIdx.y;
  const float* vb = v + ((size_t)b*S_ + s0)*E_ + e0;
  #pragma unroll
  for (int i=0;i<4;i++){
    const int r = ty + i*16;
    float4 x = *(const float4*)(vb + (size_t)r*E_ + tx*4);
    tile[r][tx*4+0]=x.x; tile[r][tx*4+1]=x.y; tile[r][tx*4+2]=x.z; tile[r][tx*4+3]=x.w;
  }
  __syncthreads();
  unsigned short* vtb = vt + ((size_t)b*E_ + e0)*S_ + s0;
  #pragma unroll
  for (int i=0;i<4;i++){
    const int er = ty + i*16;
    union { __bf16 h; unsigned short u; } c0,c1,c2,c3;
    c0.h = (__bf16)tile[tx*4+0][er];
    c1.h = (__bf16)tile[tx*4+1][er];
    c2.h = (__bf16)tile[tx*4+2][er];
    c3.h = (__bf16)tile[tx*4+3][er];
    ushort4 o = make_ushort4(c0.u, c1.u, c2.u, c3.u);
    *(ushort4*)(vtb + (size_t)er*S_ + tx*4) = o;
  }
}

// ---- shared score-tile GEMM: acc[m][n] over one 128x128 tile, K=1024 ----
__device__ inline void score_tile(const unsigned short* __restrict__ ks,
                                  const unsigned short* __restrict__ qs,
                                  int k0, int q0, int t, int lane, int wr, int wc,
                                  char* ldsK, char* ldsQ, f32x4 (&acc)[4][4]){
  for (int et = 0; et < E_/BKE; ++et){
    __syncthreads();
    stage128(ldsK, ks + (size_t)k0*E_ + et*BKE, E_, t);
    stage128(ldsQ, qs + (size_t)q0*E_ + et*BKE, E_, t);
    __syncthreads();
    #pragma unroll
    for (int kh2=0; kh2<2; ++kh2){
      bfvec8 af[4], bf[4];
      #pragma unroll
      for (int m=0;m<4;m++) af[m] = read_frag(ldsK, wr*64 + m*16 + (lane&15), kh2, lane);
      #pragma unroll
      for (int n=0;n<4;n++) bf[n] = read_frag(ldsQ, wc*64 + n*16 + (lane&15), kh2, lane);
      #pragma unroll
      for (int m=0;m<4;m++)
        #pragma unroll
        for (int n=0;n<4;n++)
          acc[m][n] = mfma16(af[m], bf[n], acc[m][n]);
    }
  }
}

// ---- k3: l[b][h][q] += sum_{k<=q in tile} exp(s) ----
__global__ __launch_bounds__(256) void k3_l(const unsigned short* __restrict__ qh,
                                            const unsigned short* __restrict__ kh,
                                            float* __restrict__ l, int g){
  int qb, kt; tri_decode(blockIdx.x, qb, kt);
  const int hp = blockIdx.y, b = blockIdx.z, h = g*G_ + hp;
  const int t = threadIdx.x, lane = t & 63, wid = t >> 6, wr = wid >> 1, wc = wid & 1;
  __shared__ __align__(16) char ldsK[BT*BKE*2];
  __shared__ __align__(16) char ldsQ[BT*BKE*2];
  __shared__ float lsh[BT];
  const unsigned short* qs = qh + ((size_t)b*G_ + hp)*S_*E_;
  const unsigned short* ks = kh + ((size_t)b*G_ + hp)*S_*E_;
  const int q0 = qb*BT, k0 = kt*BT;
  f32x4 acc[4][4];
  const f32x4 z4 = {0.f,0.f,0.f,0.f};
  #pragma unroll
  for (int m=0;m<4;m++)
    #pragma unroll
    for (int n=0;n<4;n++) acc[m][n] = z4;
  score_tile(ks, qs, k0, q0, t, lane, wr, wc, ldsK, ldsQ, acc);

  if (t < BT) lsh[t] = 0.f;
  __syncthreads();
  const bool partial = (kt == qb);
  #pragma unroll
  for (int n=0;n<4;n++){
    const int ql = wc*64 + n*16 + (lane&15);
    const int qg = q0 + ql;
    float ssum = 0.f;
    #pragma unroll
    for (int m=0;m<4;m++){
      const int kgb = k0 + wr*64 + m*16 + ((lane>>4)<<2);
      #pragma unroll
      for (int r=0;r<4;r++){
        const float e = __expf(acc[m][n][r]);
        if (!partial || (kgb + r) <= qg) ssum += e;
      }
    }
    atomicAdd(&lsh[ql], ssum);
  }
  __syncthreads();
  if (t < BT) atomicAdd(&l[((size_t)b*H_ + h)*S_ + q0 + t], lsh[t]);
}

// ---- k4: At32[b][k][q] += lr_h * exp(s)/l_h[q]  (strict k<q) ----
__global__ __launch_bounds__(256) void k4_A(const unsigned short* __restrict__ qh,
                                            const unsigned short* __restrict__ kh,
                                            const float* __restrict__ l, const float* __restrict__ lr,
                                            float* __restrict__ At32, int g){
  int qb, kb; tri_decode(blockIdx.x, qb, kb);
  const int hp = blockIdx.y, b = blockIdx.z, h = g*G_ + hp;
  const int t = threadIdx.x, lane = t & 63, wid = t >> 6, wr = wid >> 1, wc = wid & 1;
  __shared__ __align__(16) char ldsK[BT*BKE*2];
  __shared__ __align__(16) char ldsQ[BT*BKE*2];
  const unsigned short* qs = qh + ((size_t)b*G_ + hp)*S_*E_;
  const unsigned short* ks = kh + ((size_t)b*G_ + hp)*S_*E_;
  const int q0 = qb*BT, k0 = kb*BT;
  f32x4 acc[4][4];
  const f32x4 z4 = {0.f,0.f,0.f,0.f};
  #pragma unroll
  for (int m=0;m<4;m++)
    #pragma unroll
    for (int n=0;n<4;n++) acc[m][n] = z4;
  score_tile(ks, qs, k0, q0, t, lane, wr, wc, ldsK, ldsQ, acc);

  const float lrh = lr[h];
  const bool diag = (kb == qb);
  float wgt[4]; int qg[4];
  #pragma unroll
  for (int n=0;n<4;n++){
    const int ql = wc*64 + n*16 + (lane&15);
    qg[n] = q0 + ql;
    wgt[n] = lrh / l[((size_t)b*H_ + h)*S_ + qg[n]];
  }
  float* Atb = At32 + (size_t)b*S_*S_;
  #pragma unroll
  for (int m=0;m<4;m++){
    #pragma unroll
    for (int r=0;r<4;r++){
      const int kg = k0 + wr*64 + m*16 + ((lane>>4)<<2) + r;
      float* rowp = Atb + (size_t)kg*S_;
      #pragma unroll
      for (int n=0;n<4;n++){
        if (!diag || kg < qg[n])
          atomicAdd(rowp + qg[n], __expf(acc[m][n][r]) * wgt[n]);
      }
    }
  }
}

// ---- k5: out[b][k][d] = (1/(k+1)) * sum_q At32[k][q] * v[q][d] ----
__global__ __launch_bounds__(256) void k5_out(const float* __restrict__ At32,
                                              const unsigned short* __restrict__ vt,
                                              float* __restrict__ out){
  const int db = blockIdx.x, kb = blockIdx.y, b = blockIdx.z;
  const int t = threadIdx.x, lane = t & 63, wid = t >> 6, wr = wid >> 1, wc = wid & 1;
  __shared__ __align__(16) char ldsA[BT*BKE*2];   // 128 x 64 bf16
  __shared__ __align__(16) char ldsV[64*BKE*2];   // 64 x 64 bf16
  const float* Ab = At32 + (size_t)b*S_*S_;
  const unsigned short* vb = vt + (size_t)b*E_*S_;
  const int k0 = kb*BT, d0 = db*64;
  f32x4 acc[4][2];
  const f32x4 z4 = {0.f,0.f,0.f,0.f};
  #pragma unroll
  for (int m=0;m<4;m++){ acc[m][0]=z4; acc[m][1]=z4; }
  for (int qt = kb*2; qt < S_/64; ++qt){
    const int qq0 = qt*64;
    __syncthreads();
    stagecvt128(ldsA, Ab + (size_t)k0*S_ + qq0, S_, t);
    stage64   (ldsV, vb + (size_t)d0*S_ + qq0, S_, t);
    __syncthreads();
    #pragma unroll
    for (int kh2=0; kh2<2; ++kh2){
      bfvec8 af[4], bf[2];
      #pragma unroll
      for (int m=0;m<4;m++) af[m] = read_frag(ldsA, wr*64 + m*16 + (lane&15), kh2, lane);
      #pragma unroll
      for (int n=0;n<2;n++) bf[n] = read_frag(ldsV, wc*32 + n*16 + (lane&15), kh2, lane);
      #pragma unroll
      for (int m=0;m<4;m++)
        #pragma unroll
        for (int n=0;n<2;n++)
          acc[m][n] = mfma16(af[m], bf[n], acc[m][n]);
    }
  }
  #pragma unroll
  for (int m=0;m<4;m++){
    #pragma unroll
    for (int r=0;r<4;r++){
      const int kg = k0 + wr*64 + m*16 + ((lane>>4)<<2) + r;
      const float ns = 1.0f / (float)(kg + 1);
      float* p = out + ((size_t)b*S_ + kg)*E_ + d0;
      #pragma unroll
      for (int n=0;n<2;n++){
        const int dl = wc*32 + n*16 + (lane&15);
        p[dl] = acc[m][n][r] * ns;
      }
    }
  }
}

extern "C" void kernel_launch(void* const* d_in, const int* in_sizes, int n_in,
                              void* d_out, int out_size, void* d_ws, size_t ws_size,
                              hipStream_t stream){
  const float* q  = (const float*)d_in[0];
  const float* k  = (const float*)d_in[1];
  const float* v  = (const float*)d_in[2];
  const float* W  = (const float*)d_in[3];
  const float* lr = (const float*)d_in[4];
  float* out = (float*)d_out;
  (void)in_sizes; (void)n_in; (void)out_size; (void)ws_size;

  char* ws = (char*)d_ws;
  size_t off = 0;
  float* l = (float*)(ws + off);                 off += (size_t)B_*H_*S_*4;       // 256 KB
  float* At32 = (float*)(ws + off);              off += (size_t)B_*S_*S_*4;       // 33.6 MB
  unsigned short* qh = (unsigned short*)(ws+off); off += (size_t)B_*G_*S_*E_*2;   // 33.6 MB
  unsigned short* kh = (unsigned short*)(ws+off); off += (size_t)B_*G_*S_*E_*2;   // 33.6 MB
  unsigned short* vt = (unsigned short*)(ws+off); off += (size_t)B_*E_*S_*2;      // 8.4 MB

  const int n4 = (B_*H_*S_ + B_*S_*S_) / 4;   // l + At32 floats / 4
  kz<<<2048, 256, 0, stream>>>((float4*)l, n4);
  k2_tr<<<dim3(S_/64, E_/64, B_), dim3(16,16), 0, stream>>>(v, vt);

  const int NT = (S_/BT)*((S_/BT)+1)/2;   // 136
  for (int g = 0; g < H_/G_; ++g){
    k0_prep<<<dim3(S_*(E_/8)/256, G_, B_), 256, 0, stream>>>(q, k, W, qh, kh, g);
    k3_l  <<<dim3(NT, G_, B_), 256, 0, stream>>>(qh, kh, l, g);
    k4_A  <<<dim3(NT, G_, B_), 256, 0, stream>>>(qh, kh, l, lr, At32, g);
  }
  k5_out<<<dim3(E_/64, S_/BT, B_), 256, 0, stream>>>(At32, vt, out);
}

// Round 8
// 688.547 us; speedup vs baseline: 7.3015x; 1.3286x over previous
//
#include <hip/hip_runtime.h>
#include <hip/hip_bf16.h>
#include <hip/hip_fp16.h>

#define S_ 2048
#define E_ 1024
#define B_ 2
#define H_ 16
#define G_ 2      // heads per group (kept small: total ws must stay < 109.3 MB proven bound)
#define BT 128
#define BKE 64
#define NT_ 136   // (S/BT)*(S/BT+1)/2 triangular tiles

typedef __bf16 bfvec8 __attribute__((ext_vector_type(8)));
typedef float  f32x4  __attribute__((ext_vector_type(4)));

__device__ inline f32x4 mfma16(bfvec8 a, bfvec8 b, f32x4 c){
  return __builtin_amdgcn_mfma_f32_16x16x32_bf16(a, b, c, 0, 0, 0);
}

__device__ inline void tri_decode(int idx, int& qb, int& kt){
  int q = (int)((sqrtf(8.0f*(float)idx + 1.0f) - 1.0f) * 0.5f);
  while ((q+1)*(q+2)/2 <= idx) ++q;
  while (q*(q+1)/2 > idx) --q;
  qb = q; kt = idx - q*(q+1)/2;
}

// ---- LDS staging helpers: tile row pitch 128B, swizzle byte ^= (row&7)<<4 ----
__device__ inline void stage128(char* lds, const unsigned short* __restrict__ src, int pitch, int t){
  const int row = t >> 1, cb = (t & 1) * 32;
  const unsigned short* sp = src + (size_t)row*pitch + cb;
  #pragma unroll
  for (int c = 0; c < 4; ++c){
    uint4 v = *(const uint4*)(sp + c*8);
    const int byte = (row*128 + (cb + c*8)*2) ^ ((row & 7) << 4);
    *(uint4*)(lds + byte) = v;
  }
}

__device__ inline void stage64(char* lds, const unsigned short* __restrict__ src, int pitch, int t){
  const int row = t >> 2, cb = (t & 3) * 16;
  const unsigned short* sp = src + (size_t)row*pitch + cb;
  #pragma unroll
  for (int c = 0; c < 2; ++c){
    uint4 v = *(const uint4*)(sp + c*8);
    const int byte = (row*128 + (cb + c*8)*2) ^ ((row & 7) << 4);
    *(uint4*)(lds + byte) = v;
  }
}

__device__ inline void stagecvt128(char* lds, const float* __restrict__ src, int pitch, int t){
  const int row = t >> 1, cb = (t & 1) * 32;
  const float* sp = src + (size_t)row*pitch + cb;
  #pragma unroll
  for (int c = 0; c < 4; ++c){
    float4 a = *(const float4*)(sp + c*8);
    float4 b = *(const float4*)(sp + c*8 + 4);
    union { bfvec8 v; uint4 u; } pk;
    pk.v[0]=(__bf16)a.x; pk.v[1]=(__bf16)a.y; pk.v[2]=(__bf16)a.z; pk.v[3]=(__bf16)a.w;
    pk.v[4]=(__bf16)b.x; pk.v[5]=(__bf16)b.y; pk.v[6]=(__bf16)b.z; pk.v[7]=(__bf16)b.w;
    const int byte = (row*128 + (cb + c*8)*2) ^ ((row & 7) << 4);
    *(uint4*)(lds + byte) = pk.u;
  }
}

__device__ inline bfvec8 read_frag(const char* lds, int row, int kh2, int lane){
  const int byte = (row*128 + kh2*64 + ((lane >> 4) << 4)) ^ ((row & 7) << 4);
  return *(const bfvec8*)(lds + byte);
}

// ---- zero l ----
__global__ void kz(float4* __restrict__ p, int n4){
  const float4 z = make_float4(0.f,0.f,0.f,0.f);
  for (int i = blockIdx.x*256 + threadIdx.x; i < n4; i += gridDim.x*256) p[i] = z;
}

// ---- k0: q̂,k̂ bf16 for heads g*G_..g*G_+G_-1 ----
__global__ __launch_bounds__(256) void k0_prep(const float* __restrict__ q, const float* __restrict__ k,
                                               const float* __restrict__ W,
                                               unsigned short* __restrict__ qh, unsigned short* __restrict__ kh,
                                               int g){
  const int tid = blockIdx.x*256 + threadIdx.x;   // [0, S*E/8)
  const int e0 = (tid & 127) * 8;
  const int s  = tid >> 7;
  const int hp = blockIdx.y, b = blockIdx.z;
  const int h  = g*G_ + hp;
  const float* qp = q + ((size_t)b*S_ + s)*E_ + e0;
  const float* kp = k + ((size_t)b*S_ + s)*E_ + e0;
  const float* wp = W + (size_t)h*E_ + e0;
  float xq[8], xk[8], xw[8];
  *(float4*)&xq[0] = *(const float4*)qp;  *(float4*)&xq[4] = *(const float4*)(qp+4);
  *(float4*)&xk[0] = *(const float4*)kp;  *(float4*)&xk[4] = *(const float4*)(kp+4);
  *(float4*)&xw[0] = *(const float4*)wp;  *(float4*)&xw[4] = *(const float4*)(wp+4);
  union { bfvec8 v; uint4 u; } oq, ok;
  const float base = -13.287712379549449f / 1024.0f;   // -log2(10000)*2/E
  #pragma unroll
  for (int p = 0; p < 4; ++p){
    const int j = (e0 >> 1) + p;
    const float inv = exp2f((float)(2*j) * base);
    float sn, cn;
    sincosf((float)s * inv, &sn, &cn);
    float t0 = xw[2*p]*xq[2*p], t1 = xw[2*p+1]*xq[2*p+1];
    oq.v[2*p]   = (__bf16)(t0*cn - t1*sn);
    oq.v[2*p+1] = (__bf16)(t1*cn + t0*sn);
    t0 = xw[2*p]*xk[2*p]; t1 = xw[2*p+1]*xk[2*p+1];
    ok.v[2*p]   = (__bf16)(t0*cn - t1*sn);
    ok.v[2*p+1] = (__bf16)(t1*cn + t0*sn);
  }
  const size_t o = (((size_t)b*G_ + hp)*S_ + s)*E_ + e0;
  *(uint4*)(qh + o) = oq.u;
  *(uint4*)(kh + o) = ok.u;
}

// ---- k2: vt[b][e][s] = bf16(v[b][s][e]) ----
__global__ void k2_tr(const float* __restrict__ v, unsigned short* __restrict__ vt){
  __shared__ float tile[64][65];
  const int b = blockIdx.z, s0 = blockIdx.x*64, e0 = blockIdx.y*64;
  const int tx = threadIdx.x, ty = threadIdx.y;
  const float* vb = v + ((size_t)b*S_ + s0)*E_ + e0;
  #pragma unroll
  for (int i=0;i<4;i++){
    const int r = ty + i*16;
    float4 x = *(const float4*)(vb + (size_t)r*E_ + tx*4);
    tile[r][tx*4+0]=x.x; tile[r][tx*4+1]=x.y; tile[r][tx*4+2]=x.z; tile[r][tx*4+3]=x.w;
  }
  __syncthreads();
  unsigned short* vtb = vt + ((size_t)b*E_ + e0)*S_ + s0;
  #pragma unroll
  for (int i=0;i<4;i++){
    const int er = ty + i*16;
    union { __bf16 h; unsigned short u; } c0,c1,c2,c3;
    c0.h = (__bf16)tile[tx*4+0][er];
    c1.h = (__bf16)tile[tx*4+1][er];
    c2.h = (__bf16)tile[tx*4+2][er];
    c3.h = (__bf16)tile[tx*4+3][er];
    ushort4 o = make_ushort4(c0.u, c1.u, c2.u, c3.u);
    *(ushort4*)(vtb + (size_t)er*S_ + tx*4) = o;
  }
}

// ---- shared score-tile GEMM: acc[m][n] over one 128x128 tile, K=1024 ----
__device__ inline void score_tile(const unsigned short* __restrict__ ks,
                                  const unsigned short* __restrict__ qs,
                                  int k0, int q0, int t, int lane, int wr, int wc,
                                  char* ldsK, char* ldsQ, f32x4 (&acc)[4][4]){
  for (int et = 0; et < E_/BKE; ++et){
    __syncthreads();
    stage128(ldsK, ks + (size_t)k0*E_ + et*BKE, E_, t);
    stage128(ldsQ, qs + (size_t)q0*E_ + et*BKE, E_, t);
    __syncthreads();
    #pragma unroll
    for (int kh2=0; kh2<2; ++kh2){
      bfvec8 af[4], bf[4];
      #pragma unroll
      for (int m=0;m<4;m++) af[m] = read_frag(ldsK, wr*64 + m*16 + (lane&15), kh2, lane);
      #pragma unroll
      for (int n=0;n<4;n++) bf[n] = read_frag(ldsQ, wc*64 + n*16 + (lane&15), kh2, lane);
      #pragma unroll
      for (int m=0;m<4;m++)
        #pragma unroll
        for (int n=0;n<4;n++)
          acc[m][n] = mfma16(af[m], bf[n], acc[m][n]);
    }
  }
}

// ---- k3s: ONE score GEMM pass: P[tile] = exp(s) fp16, l += masked column sums ----
__global__ __launch_bounds__(256) void k3s(const unsigned short* __restrict__ qh,
                                           const unsigned short* __restrict__ kh,
                                           float* __restrict__ l, unsigned short* __restrict__ P,
                                           int g){
  int qb, kt; tri_decode(blockIdx.x, qb, kt);
  const int hp = blockIdx.y, b = blockIdx.z, h = g*G_ + hp;
  const int t = threadIdx.x, lane = t & 63, wid = t >> 6, wr = wid >> 1, wc = wid & 1;
  __shared__ __align__(16) char ldsK[BT*BKE*2];
  __shared__ __align__(16) char ldsQ[BT*BKE*2];
  __shared__ float lsh[BT];
  const unsigned short* qs = qh + ((size_t)b*G_ + hp)*S_*E_;
  const unsigned short* ks = kh + ((size_t)b*G_ + hp)*S_*E_;
  const int q0 = qb*BT, k0 = kt*BT;
  f32x4 acc[4][4];
  const f32x4 z4 = {0.f,0.f,0.f,0.f};
  #pragma unroll
  for (int m=0;m<4;m++)
    #pragma unroll
    for (int n=0;n<4;n++) acc[m][n] = z4;
  score_tile(ks, qs, k0, q0, t, lane, wr, wc, ldsK, ldsQ, acc);

  unsigned short* Pt = P + ((size_t)(b*G_ + hp)*NT_ + blockIdx.x)*(BT*BT);
  if (t < BT) lsh[t] = 0.f;
  __syncthreads();
  const bool partial = (kt == qb);
  #pragma unroll
  for (int n=0;n<4;n++){
    const int ql = wc*64 + n*16 + (lane&15);
    const int qg = q0 + ql;
    float ssum = 0.f;
    #pragma unroll
    for (int m=0;m<4;m++){
      const int klb = wr*64 + m*16 + ((lane>>4)<<2);
      #pragma unroll
      for (int r=0;r<4;r++){
        const float e = __expf(acc[m][n][r]);
        union { __half hh; unsigned short u; } cv;
        cv.hh = __float2half(e);
        Pt[(klb + r)*BT + ql] = cv.u;
        if (!partial || (k0 + klb + r) <= qg) ssum += e;
      }
    }
    atomicAdd(&lsh[ql], ssum);
  }
  __syncthreads();
  if (t < BT) atomicAdd(&l[((size_t)b*H_ + h)*S_ + q0 + t], lsh[t]);
}

// ---- k4s: At32[tile] (first? = : +=) sum_hp lr_h * P_h / l_h[q]  (strict k<q on diag tiles) ----
__global__ __launch_bounds__(256) void k4s(const unsigned short* __restrict__ P,
                                           const float* __restrict__ l, const float* __restrict__ lr,
                                           float* __restrict__ At32, int g, int first){
  int qb, kb; tri_decode(blockIdx.x, qb, kb);
  const int rc = blockIdx.y, b = blockIdx.z;
  const int t = threadIdx.x;
  const int q0 = qb*BT, k0 = kb*BT;
  __shared__ float wsh[G_][BT];
  if (t < BT){
    #pragma unroll
    for (int hp = 0; hp < G_; ++hp){
      const int h = g*G_ + hp;
      wsh[hp][t] = lr[h] / l[((size_t)b*H_ + h)*S_ + q0 + t];
    }
  }
  __syncthreads();
  const size_t tbase = ((size_t)(b*G_)*NT_ + blockIdx.x)*(BT*BT);
  const size_t hstride = (size_t)NT_*BT*BT;
  const bool diag = (qb == kb);
  float* Atb = At32 + (size_t)b*S_*S_ + (size_t)k0*S_ + q0;
  const int r0 = rc*32;
  #pragma unroll
  for (int it = 0; it < 2; ++it){
    const int idx = t + it*256;             // 0..511 over 32 rows x 16 u4
    const int row = r0 + (idx >> 4);
    const int c8  = (idx & 15) * 8;
    float sum[8] = {0.f,0.f,0.f,0.f,0.f,0.f,0.f,0.f};
    #pragma unroll
    for (int hp = 0; hp < G_; ++hp){
      const unsigned short* Pp = P + tbase + hp*hstride + (size_t)row*BT + c8;
      uint4 pv = *(const uint4*)Pp;
      const __half* ph = (const __half*)&pv;
      #pragma unroll
      for (int j = 0; j < 8; ++j)
        sum[j] += wsh[hp][c8 + j] * __half2float(ph[j]);
    }
    if (diag){
      #pragma unroll
      for (int j = 0; j < 8; ++j)
        if (row >= c8 + j) sum[j] = 0.f;
    }
    float* ap = Atb + (size_t)row*S_ + c8;
    float4 a0, a1;
    if (first){
      a0 = make_float4(sum[0], sum[1], sum[2], sum[3]);
      a1 = make_float4(sum[4], sum[5], sum[6], sum[7]);
    } else {
      a0 = *(float4*)ap; a1 = *(float4*)(ap + 4);
      a0.x += sum[0]; a0.y += sum[1]; a0.z += sum[2]; a0.w += sum[3];
      a1.x += sum[4]; a1.y += sum[5]; a1.z += sum[6]; a1.w += sum[7];
    }
    *(float4*)ap = a0; *(float4*)(ap + 4) = a1;
  }
}

// ---- k5: out[b][k][d] = (1/(k+1)) * sum_q At32[k][q] * v[q][d] ----
__global__ __launch_bounds__(256) void k5_out(const float* __restrict__ At32,
                                              const unsigned short* __restrict__ vt,
                                              float* __restrict__ out){
  const int db = blockIdx.x, kb = blockIdx.y, b = blockIdx.z;
  const int t = threadIdx.x, lane = t & 63, wid = t >> 6, wr = wid >> 1, wc = wid & 1;
  __shared__ __align__(16) char ldsA[BT*BKE*2];   // 128 x 64 bf16
  __shared__ __align__(16) char ldsV[64*BKE*2];   // 64 x 64 bf16
  const float* Ab = At32 + (size_t)b*S_*S_;
  const unsigned short* vb = vt + (size_t)b*E_*S_;
  const int k0 = kb*BT, d0 = db*64;
  f32x4 acc[4][2];
  const f32x4 z4 = {0.f,0.f,0.f,0.f};
  #pragma unroll
  for (int m=0;m<4;m++){ acc[m][0]=z4; acc[m][1]=z4; }
  for (int qt = kb*2; qt < S_/64; ++qt){
    const int qq0 = qt*64;
    __syncthreads();
    stagecvt128(ldsA, Ab + (size_t)k0*S_ + qq0, S_, t);
    stage64   (ldsV, vb + (size_t)d0*S_ + qq0, S_, t);
    __syncthreads();
    #pragma unroll
    for (int kh2=0; kh2<2; ++kh2){
      bfvec8 af[4], bf[2];
      #pragma unroll
      for (int m=0;m<4;m++) af[m] = read_frag(ldsA, wr*64 + m*16 + (lane&15), kh2, lane);
      #pragma unroll
      for (int n=0;n<2;n++) bf[n] = read_frag(ldsV, wc*32 + n*16 + (lane&15), kh2, lane);
      #pragma unroll
      for (int m=0;m<4;m++)
        #pragma unroll
        for (int n=0;n<2;n++)
          acc[m][n] = mfma16(af[m], bf[n], acc[m][n]);
    }
  }
  #pragma unroll
  for (int m=0;m<4;m++){
    #pragma unroll
    for (int r=0;r<4;r++){
      const int kg = k0 + wr*64 + m*16 + ((lane>>4)<<2) + r;
      const float ns = 1.0f / (float)(kg + 1);
      float* p = out + ((size_t)b*S_ + kg)*E_ + d0;
      #pragma unroll
      for (int n=0;n<2;n++){
        const int dl = wc*32 + n*16 + (lane&15);
        p[dl] = acc[m][n][r] * ns;
      }
    }
  }
}

extern "C" void kernel_launch(void* const* d_in, const int* in_sizes, int n_in,
                              void* d_out, int out_size, void* d_ws, size_t ws_size,
                              hipStream_t stream){
  const float* q  = (const float*)d_in[0];
  const float* k  = (const float*)d_in[1];
  const float* v  = (const float*)d_in[2];
  const float* W  = (const float*)d_in[3];
  const float* lr = (const float*)d_in[4];
  float* out = (float*)d_out;
  (void)in_sizes; (void)n_in; (void)out_size; (void)ws_size;

  char* ws = (char*)d_ws;
  size_t off = 0;
  float* l = (float*)(ws + off);                  off += (size_t)B_*H_*S_*4;        // 0.26 MB
  float* At32 = (float*)(ws + off);               off += (size_t)B_*S_*S_*4;        // 33.6 MB
  unsigned short* P  = (unsigned short*)(ws+off); off += (size_t)B_*G_*NT_*BT*BT*2; // 17.8 MB
  unsigned short* qh = (unsigned short*)(ws+off); off += (size_t)B_*G_*S_*E_*2;     // 16.8 MB
  unsigned short* kh = (unsigned short*)(ws+off); off += (size_t)B_*G_*S_*E_*2;     // 16.8 MB
  unsigned short* vt = (unsigned short*)(ws+off); off += (size_t)B_*E_*S_*2;        // 8.4 MB
  // total 93.6 MB < 109.3 MB proven-safe (round 3)

  const int n4 = (B_*H_*S_) / 4;   // l floats / 4
  kz<<<64, 256, 0, stream>>>((float4*)l, n4);
  k2_tr<<<dim3(S_/64, E_/64, B_), dim3(16,16), 0, stream>>>(v, vt);

  for (int g = 0; g < H_/G_; ++g){
    k0_prep<<<dim3(S_*(E_/8)/256, G_, B_), 256, 0, stream>>>(q, k, W, qh, kh, g);
    k3s  <<<dim3(NT_, G_, B_), 256, 0, stream>>>(qh, kh, l, P, g);
    k4s  <<<dim3(NT_, 4, B_), 256, 0, stream>>>(P, l, lr, At32, g, g == 0 ? 1 : 0);
  }
  k5_out<<<dim3(E_/64, S_/BT, B_), 256, 0, stream>>>(At32, vt, out);
}